// Round 11
// baseline (99.091 us; speedup 1.0000x reference)
//
#include <hip/hip_runtime.h>

// Sizes (fixed by the problem)
#define NB 16
#define NQ 128
#define NK 512
#define NH 128
#define NDV 128

#define KPAD 132  // 128+4 floats: b128 lane*KPAD reads measured 0 conflicts

typedef __attribute__((ext_vector_type(8))) short short8;
typedef __attribute__((ext_vector_type(4))) unsigned short u16x4;  // NOT ushort4: HIP defines that
typedef __attribute__((ext_vector_type(4))) float f32x4;
typedef __attribute__((ext_vector_type(2))) float f32x2;

#define C2LOG2E 2.8853900817779268f  // 2*log2(e): folded into proj epilogue
#define LOG2E   1.4426950408889634f

__device__ __forceinline__ short f2bf(float x) {   // RNE f32 -> bf16
    unsigned u = __float_as_uint(x);
    unsigned r = (u + 0x7fffu + ((u >> 16) & 1u)) >> 16;
    return (short)r;
}
__device__ __forceinline__ float bf2f(unsigned short s) {
    return __uint_as_float(((unsigned)s) << 16);
}

// ---------------------------------------------------------------------------
// r11 = r10 (98.3us best: bf16 P confirmed +0.9) + av V-reuse doubled.
// av was V-L2-BW-bound (~128MB L2 reads = 3.7us vs 1.7us VALU floor):
// 8 q-rows per block (was 4) halves V replication. Grid 256 = b x qt(16),
// 1024 thr = 16 waves, k strips stride 128, LDS 80KB (1 block/CU,
// 4 waves/SIMD — unchanged occupancy).
//   tanh identity: sum_h wv*tanh(q+k) = Wsum - sum_h 2wv/(Eq*Ek+1),
//   Eq/Ek = exp2(2log2e * proj); masked softmax exploits exact-0 underflow.
// Poison-hardening kept: Ek rows >= nv zeroed in score; av guarded tail
// (tail strip start = nv&~7 <= 504, V row indices <= 511, rows >= nv -> 0).
// Ledger: r2 av +2.7 | r4 scalar +1.0 | r10 bf16-P +0.9 | fusion -9 |
//         occupancy -1.5 | fold 0. Harness re-poison floor ~65us.
// ---------------------------------------------------------------------------

// ---------------------------------------------------------------------------
// Kernel 1: pack W into MFMA B-fragment order, split bf16 hi/lo.
// ---------------------------------------------------------------------------
__global__ __launch_bounds__(256) void wsplit_kernel(
    const float* __restrict__ Wq, const float* __restrict__ Wk,
    const float* __restrict__ wv,
    short* __restrict__ pqh, short* __restrict__ pql,
    short* __restrict__ pkh, short* __restrict__ pkl,
    float* __restrict__ w2)
{
    int blk = blockIdx.x;          // 16 blocks = w(2) x ht(8)
    int t   = threadIdx.x;         // ks(4) x lane(64)
    if (blk == 0 && t < NH) w2[t] = 2.0f * wv[t];
    int w = blk >> 3, ht = blk & 7;
    int ks = t >> 6, lane = t & 63;
    int m = lane & 15, quad = lane >> 4;
    const float* W = w ? Wk : Wq;
    short* ph = w ? pkh : pqh;
    short* pl = w ? pkl : pql;
    short8 hi, lo;
#pragma unroll
    for (int j = 0; j < 8; ++j) {
        float x = W[(size_t)(ks * 32 + quad * 8 + j) * NH + ht * 16 + m];
        short h = f2bf(x);
        hi[j] = h;
        lo[j] = f2bf(x - bf2f((unsigned short)h));
    }
    size_t o = (size_t)((ht * 4 + ks) * 64 + lane) * 8;
    *(short8*)(ph + o) = hi;
    *(short8*)(pl + o) = lo;
}

// ---------------------------------------------------------------------------
// Kernel 2: projection + exp. E = exp2(2log2e * X@W), split-bf16 MFMA
// (Ah*Bh + Al*Bh + Ah*Bh, rel err ~2^-16). X tile staged once in LDS.
// ---------------------------------------------------------------------------
__global__ __launch_bounds__(256) void proj_kernel(
    const float* __restrict__ Xq, const float* __restrict__ Xk,
    const short* __restrict__ pqh, const short* __restrict__ pql,
    const short* __restrict__ pkh, const short* __restrict__ pkl,
    float* __restrict__ Eq, float* __restrict__ Ek)
{
    __shared__ float s_x[16 * KPAD];     // 8448 B

    int blk = blockIdx.x;
    const float* X; const short* ph; const short* pl; float* Y; int row0;
    if (blk < 128) { X = Xq; ph = pqh; pl = pql; Y = Eq; row0 = blk * 16; }
    else           { X = Xk; ph = pkh; pl = pkl; Y = Ek; row0 = (blk - 128) * 16; }
    int t = threadIdx.x;
    int wave = t >> 6, lane = t & 63;
    int m = lane & 15, quad = lane >> 4;

#pragma unroll
    for (int r = 0; r < 2; ++r) {
        int i = (t + r * 256) * 4;
        int row = i >> 7, col = i & 127;
        *(f32x4*)&s_x[row * KPAD + col] =
            *(const f32x4*)&X[(size_t)(row0 + row) * NH + col];
    }
    __syncthreads();

    short8 AH[4], AL[4];
#pragma unroll
    for (int ks = 0; ks < 4; ++ks) {
        int base = m * KPAD + ks * 32 + quad * 8;
        f32x4 x0 = *(const f32x4*)&s_x[base];
        f32x4 x1 = *(const f32x4*)&s_x[base + 4];
#pragma unroll
        for (int j = 0; j < 4; ++j) {
            short h0 = f2bf(x0[j]);
            AH[ks][j] = h0; AL[ks][j] = f2bf(x0[j] - bf2f((unsigned short)h0));
            short h1 = f2bf(x1[j]);
            AH[ks][j + 4] = h1; AL[ks][j + 4] = f2bf(x1[j] - bf2f((unsigned short)h1));
        }
    }
#pragma unroll
    for (int hi = 0; hi < 2; ++hi) {
        int ht = wave * 2 + hi;
        f32x4 acc = {0.f, 0.f, 0.f, 0.f};
#pragma unroll
        for (int ks = 0; ks < 4; ++ks) {
            size_t o = (size_t)((ht * 4 + ks) * 64 + lane) * 8;
            short8 bh = *(const short8*)(ph + o);
            short8 bl = *(const short8*)(pl + o);
            acc = __builtin_amdgcn_mfma_f32_16x16x32_bf16(AH[ks], bl, acc, 0, 0, 0);
            acc = __builtin_amdgcn_mfma_f32_16x16x32_bf16(AL[ks], bh, acc, 0, 0, 0);
            acc = __builtin_amdgcn_mfma_f32_16x16x32_bf16(AH[ks], bh, acc, 0, 0, 0);
        }
        // D: col = lane&15, row = quad*4 + r  [verified layout]
#pragma unroll
        for (int r = 0; r < 4; ++r)
            Y[(size_t)(row0 + quad * 4 + r) * NH + ht * 16 + m] =
                __builtin_amdgcn_exp2f(acc[r] * C2LOG2E);
    }
}

// ---------------------------------------------------------------------------
// Kernel 3 (r4 config): scores. Packed-f32 inner loop + pair-reciprocal,
// wave-uniform operands (q rows, w2) via the scalar pipe. Grid 512 =
// b(16) x qt(8) x kc(4); 512 thr; s_ek 67.5 KB. P stored as bf16 (r10).
// s_ek rows >= nv zeroed at staging (poison-hard).
// ---------------------------------------------------------------------------
__global__ __launch_bounds__(512) void score_kernel(
    const float* __restrict__ Eqp, const float* __restrict__ Ekp,
    const int* __restrict__ vlen, const float* __restrict__ w2,
    short* __restrict__ Pbf)
{
    __shared__ float s_ek[128 * KPAD];   // 67584 B (only LDS in this kernel)

    int blk = blockIdx.x;
    int b    = blk & 15;                 // batch-interleaved
    int rest = blk >> 4;
    int qt = rest & 7, kc = rest >> 3;   // qt 0..7 (16q each), kc 0..3 (128k)
    int q0 = qt * 16, k0 = kc * 128;
    int t  = threadIdx.x;

    int nv = vlen[b];
    nv = max(1, min(NK, nv));
    short* Pb = Pbf + ((size_t)b * NQ + q0) * NK;

    if (k0 >= nv) {
        // fully masked chunk: 16q x 128k = 2048 bf16 = one u16x4/thread
        int q = t >> 5, kk = (t & 31) * 4;
        u16x4 z = {0, 0, 0, 0};
        *(u16x4*)&Pb[(size_t)q * NK + k0 + kk] = z;
        return;
    }

    for (int i = t; i < 128 * 32; i += 512) {
        int row = i >> 5, c4 = i & 31;
        f32x4 v = *(const f32x4*)&Ekp[((size_t)b * NK + k0 + row) * NH + c4 * 4];
        if (k0 + row >= nv) {            // sanitize don't-care keys rows
            f32x4 z = {0.f, 0.f, 0.f, 0.f};
            v = z;
        }
        *(f32x4*)&s_ek[row * KPAD + c4 * 4] = v;
    }
    __syncthreads();

    int lane = t & 63, w = t >> 6;
    int wu = __builtin_amdgcn_readfirstlane(w);  // provably uniform
    int g = wu & 3, hf = wu >> 2;

    // Wsum = sum_h wv = 0.5 * sum_h w2 (one-time per-lane global read)
    float s2 = w2[lane] + w2[lane + 64];
#pragma unroll
    for (int off = 32; off; off >>= 1) s2 += __shfl_xor(s2, off);
    float wsum = 0.5f * s2;

    const float* ek = &s_ek[(hf * 64 + lane) * KPAD];
    // uniform scalar bases for the 4 q-rows of this wave
    const float* e0 = Eqp + ((size_t)b * NQ + q0 + g * 4 + 0) * NH;
    const float* e1 = Eqp + ((size_t)b * NQ + q0 + g * 4 + 1) * NH;
    const float* e2 = Eqp + ((size_t)b * NQ + q0 + g * 4 + 2) * NH;
    const float* e3 = Eqp + ((size_t)b * NQ + q0 + g * 4 + 3) * NH;

    const f32x2 one2 = {1.0f, 1.0f};
    f32x2 v00 = {0.f, 0.f}, v01 = {0.f, 0.f};
    f32x2 v10 = {0.f, 0.f}, v11 = {0.f, 0.f};
    f32x2 v20 = {0.f, 0.f}, v21 = {0.f, 0.f};
    f32x2 v30 = {0.f, 0.f}, v31 = {0.f, 0.f};

#define PKSTEP(accv, qv, kv, wv)                                        \
    {                                                                   \
        f32x2 x = qv * kv + one2;                                       \
        float R = __builtin_amdgcn_rcpf(x[0] * x[1]);                   \
        f32x2 xs = {x[1], x[0]};                                        \
        accv += wv * (R * xs);                                          \
    }

#pragma unroll
    for (int hh = 0; hh < NH; hh += 8) {
        f32x4 kAv = *(const f32x4*)(ek + hh);          // per-lane LDS
        f32x4 kBv = *(const f32x4*)(ek + hh + 4);
        f32x4 wAv = *(const f32x4*)(w2 + hh);          // uniform -> s_load
        f32x4 wBv = *(const f32x4*)(w2 + hh + 4);
        f32x2 kA0 = {kAv[0], kAv[1]}, kA1 = {kAv[2], kAv[3]};
        f32x2 kB0 = {kBv[0], kBv[1]}, kB1 = {kBv[2], kBv[3]};
        f32x2 wA0 = {wAv[0], wAv[1]}, wA1 = {wAv[2], wAv[3]};
        f32x2 wB0 = {wBv[0], wBv[1]}, wB1 = {wBv[2], wBv[3]};
        {
            f32x4 qa = *(const f32x4*)(e0 + hh), qb = *(const f32x4*)(e0 + hh + 4);
            f32x2 qa0 = {qa[0], qa[1]}, qa1 = {qa[2], qa[3]};
            f32x2 qb0 = {qb[0], qb[1]}, qb1 = {qb[2], qb[3]};
            PKSTEP(v00, qa0, kA0, wA0); PKSTEP(v01, qa1, kA1, wA1);
            PKSTEP(v00, qb0, kB0, wB0); PKSTEP(v01, qb1, kB1, wB1);
        }
        {
            f32x4 qa = *(const f32x4*)(e1 + hh), qb = *(const f32x4*)(e1 + hh + 4);
            f32x2 qa0 = {qa[0], qa[1]}, qa1 = {qa[2], qa[3]};
            f32x2 qb0 = {qb[0], qb[1]}, qb1 = {qb[2], qb[3]};
            PKSTEP(v10, qa0, kA0, wA0); PKSTEP(v11, qa1, kA1, wA1);
            PKSTEP(v10, qb0, kB0, wB0); PKSTEP(v11, qb1, kB1, wB1);
        }
        {
            f32x4 qa = *(const f32x4*)(e2 + hh), qb = *(const f32x4*)(e2 + hh + 4);
            f32x2 qa0 = {qa[0], qa[1]}, qa1 = {qa[2], qa[3]};
            f32x2 qb0 = {qb[0], qb[1]}, qb1 = {qb[2], qb[3]};
            PKSTEP(v20, qa0, kA0, wA0); PKSTEP(v21, qa1, kA1, wA1);
            PKSTEP(v20, qb0, kB0, wB0); PKSTEP(v21, qb1, kB1, wB1);
        }
        {
            f32x4 qa = *(const f32x4*)(e3 + hh), qb = *(const f32x4*)(e3 + hh + 4);
            f32x2 qa0 = {qa[0], qa[1]}, qa1 = {qa[2], qa[3]};
            f32x2 qb0 = {qb[0], qb[1]}, qb1 = {qb[2], qb[3]};
            PKSTEP(v30, qa0, kA0, wA0); PKSTEP(v31, qa1, kA1, wA1);
            PKSTEP(v30, qb0, kB0, wB0); PKSTEP(v31, qb1, kB1, wB1);
        }
    }
#undef PKSTEP
    float c0 = (v00[0] + v00[1]) + (v01[0] + v01[1]);
    float c1 = (v10[0] + v10[1]) + (v11[0] + v11[1]);
    float c2 = (v20[0] + v20[1]) + (v21[0] + v21[1]);
    float c3 = (v30[0] + v30[1]) + (v31[0] + v31[1]);
    int kg = k0 + hf * 64 + lane;
    bool valid = kg < nv;
    float p0 = valid ? __builtin_amdgcn_exp2f((wsum - c0) * LOG2E) : 0.f;
    float p1 = valid ? __builtin_amdgcn_exp2f((wsum - c1) * LOG2E) : 0.f;
    float p2 = valid ? __builtin_amdgcn_exp2f((wsum - c2) * LOG2E) : 0.f;
    float p3 = valid ? __builtin_amdgcn_exp2f((wsum - c3) * LOG2E) : 0.f;
    short* Pr = Pb + (size_t)(g * 4) * NK + kg;
    Pr[0 * NK] = f2bf(p0);               // coalesced 2B stores per q-row
    Pr[1 * NK] = f2bf(p1);
    Pr[2 * NK] = f2bf(p2);
    Pr[3 * NK] = f2bf(p3);
}

// ---------------------------------------------------------------------------
// Kernel 4 (r11): normalize + AV, 8 q-rows per block (V reuse x2).
// Grid 256 = b(16) x qt(16); 1024 thr = 16 waves; k split across waves in
// interleaved 8-row strips (stride 128). Each V element feeds 8 fmas.
// LDS 80KB: s_p 16KB + s_red 64KB -> 1 block/CU, 4 waves/SIMD (unchanged).
// Waves 0-7 compute row sums. Poison-proof: full strips touch only rows
// < nv; the partial strip selects V rows >= nv to zero.
// ---------------------------------------------------------------------------
__global__ __launch_bounds__(1024, 4) void av_kernel(
    const short* __restrict__ Pbf, const float* __restrict__ V,
    const int* __restrict__ vlen, float* __restrict__ out)
{
    __shared__ float s_p[8 * NK];           // 16 KB: 8 q-rows of P (f32)
    __shared__ float s_red[16 * 8 * 128];   // 64 KB: per-wave partial O
    __shared__ float s_rsum[8];

    int blk = blockIdx.x;
    int b = blk & 15, qq = blk >> 4;        // qq 0..15 (8 q each)
    int q0 = qq * 8;
    int t = threadIdx.x;

    int nv = vlen[b];
    nv = max(1, min(NK, nv));

    // stage 8 P rows: 4096 bf16 = 1024 u16x4, one per thread; cvt to f32
    const u16x4* Pv = (const u16x4*)(Pbf + ((size_t)b * NQ + q0) * NK);
    {
        u16x4 pv = Pv[t];
        f32x4 pf = {bf2f(pv[0]), bf2f(pv[1]), bf2f(pv[2]), bf2f(pv[3])};
        *(f32x4*)&s_p[t * 4] = pf;
    }
    __syncthreads();

    int lane = t & 63, w = t >> 6;          // w 0..15

    if (w < 8) {                            // row sum for row w (zeros beyond
        const float* pr = &s_p[w * NK];     //  nv are exact -> sum exact)
        f32x4 s0 = *(const f32x4*)(pr + lane * 8);
        f32x4 s1 = *(const f32x4*)(pr + lane * 8 + 4);
        float s = ((s0[0] + s0[1]) + (s0[2] + s0[3])) +
                  ((s1[0] + s1[1]) + (s1[2] + s1[3]));
#pragma unroll
        for (int off = 32; off; off >>= 1) s += __shfl_xor(s, off);
        if (lane == 0) s_rsum[w] = s;       // read after final barrier
    }

    int par = lane >> 5;                    // k parity for this half-wave
    int dl  = lane & 31;
    int dv0 = dl * 4;                       // 4 dv per lane (f32x4)
    const float* Vb = V + (size_t)b * NK * NDV + dv0;
    f32x4 O[8];
#pragma unroll
    for (int q = 0; q < 8; ++q) { f32x4 z = {0.f,0.f,0.f,0.f}; O[q] = z; }

    int k = w * 8;                          // interleaved strips, stride 128
    for (; k + 8 <= nv; k += 128) {
        f32x4 v0 = *(const f32x4*)(Vb + (size_t)(k + 0 + par) * NDV);
        f32x4 v1 = *(const f32x4*)(Vb + (size_t)(k + 2 + par) * NDV);
        f32x4 v2 = *(const f32x4*)(Vb + (size_t)(k + 4 + par) * NDV);
        f32x4 v3 = *(const f32x4*)(Vb + (size_t)(k + 6 + par) * NDV);
#pragma unroll
        for (int q = 0; q < 8; ++q) {
            f32x4 p0 = *(const f32x4*)&s_p[q * NK + k];      // broadcasts
            f32x4 p1 = *(const f32x4*)&s_p[q * NK + k + 4];
            float a0 = p0[par], a1 = p0[2 + par];
            float a2 = p1[par], a3 = p1[2 + par];
#pragma unroll
            for (int j = 0; j < 4; ++j) {
                O[q][j] = fmaf(a0, v0[j], O[q][j]);
                O[q][j] = fmaf(a1, v1[j], O[q][j]);
                O[q][j] = fmaf(a2, v2[j], O[q][j]);
                O[q][j] = fmaf(a3, v3[j], O[q][j]);
            }
        }
    }
    if (k < nv) {                           // partial strip: guarded tail
        f32x4 z4 = {0.f, 0.f, 0.f, 0.f};
        f32x4 v0 = *(const f32x4*)(Vb + (size_t)(k + 0 + par) * NDV);
        f32x4 v1 = *(const f32x4*)(Vb + (size_t)(k + 2 + par) * NDV);
        f32x4 v2 = *(const f32x4*)(Vb + (size_t)(k + 4 + par) * NDV);
        f32x4 v3 = *(const f32x4*)(Vb + (size_t)(k + 6 + par) * NDV);
        if (k + 0 + par >= nv) v0 = z4;     // poison-proof: p==0 rows -> v==0
        if (k + 2 + par >= nv) v1 = z4;
        if (k + 4 + par >= nv) v2 = z4;
        if (k + 6 + par >= nv) v3 = z4;
#pragma unroll
        for (int q = 0; q < 8; ++q) {
            f32x4 p0 = *(const f32x4*)&s_p[q * NK + k];
            f32x4 p1 = *(const f32x4*)&s_p[q * NK + k + 4];
            float a0 = p0[par], a1 = p0[2 + par];
            float a2 = p1[par], a3 = p1[2 + par];
#pragma unroll
            for (int j = 0; j < 4; ++j) {
                O[q][j] = fmaf(a0, v0[j], O[q][j]);
                O[q][j] = fmaf(a1, v1[j], O[q][j]);
                O[q][j] = fmaf(a2, v2[j], O[q][j]);
                O[q][j] = fmaf(a3, v3[j], O[q][j]);
            }
        }
    }
    // combine even/odd k-parity partial sums across the half-waves
#pragma unroll
    for (int q = 0; q < 8; ++q) {
#pragma unroll
        for (int j = 0; j < 4; ++j)
            O[q][j] += __shfl_xor(O[q][j], 32);
    }
    // per-wave partials to LDS: par0 lanes write rows 0-3, par1 rows 4-7
    float* rb = &s_red[w * 1024];
    if (par == 0) {
#pragma unroll
        for (int q = 0; q < 4; ++q)
            *(f32x4*)&rb[q * 128 + dv0] = O[q];
    } else {
#pragma unroll
        for (int q = 4; q < 8; ++q)
            *(f32x4*)&rb[q * 128 + dv0] = O[q];
    }
    __syncthreads();

    // final reduce + normalize: one output scalar per thread (8 rows x 128 dv)
    int row = t >> 7, dv = t & 127;
    float s = 0.f;
#pragma unroll
    for (int ww = 0; ww < 16; ++ww) s += s_red[ww * 1024 + row * 128 + dv];
    out[((size_t)b * NQ + q0 + row) * NDV + dv] = s * (1.0f / s_rsum[row]);
}

extern "C" void kernel_launch(void* const* d_in, const int* in_sizes, int n_in,
                              void* d_out, int out_size, void* d_ws, size_t ws_size,
                              hipStream_t stream) {
    const float* q  = (const float*)d_in[0];  // (16,128,128) f32
    const float* ks = (const float*)d_in[1];  // (16,512,128) f32
    const float* vs = (const float*)d_in[2];  // (16,512,128) f32
    const int*   vl = (const int*)d_in[3];    // (16,) i32
    const float* wq = (const float*)d_in[4];  // (128,128) f32
    const float* wk = (const float*)d_in[5];  // (128,128) f32
    const float* wv = (const float*)d_in[6];  // (128,) f32

    // ws layout (~7.3 MiB; P is bf16)
    float* Eq  = (float*)d_ws;                    // 2048*128 f32
    float* Ek  = Eq + 2048 * 128;                 // 8192*128 f32
    short* Pbf = (short*)(Ek + (size_t)8192 * 128);  // 16*128*512 bf16 (2 MB)
    float* w2  = (float*)(Pbf + (size_t)NB * NQ * NK);  // 128 f32
    short* pqh = (short*)(w2 + 128);              // 4 x 16384 bf16 frags
    short* pql = pqh + 16384;
    short* pkh = pql + 16384;
    short* pkl = pkh + 16384;

    wsplit_kernel<<<16, 256, 0, stream>>>(wq, wk, wv, pqh, pql, pkh, pkl, w2);
    proj_kernel<<<640, 256, 0, stream>>>(q, ks, pqh, pql, pkh, pkl, Eq, Ek);
    score_kernel<<<512, 512, 0, stream>>>(Eq, Ek, vl, w2, Pbf);
    av_kernel<<<256, 1024, 0, stream>>>(Pbf, vs, vl, (float*)d_out);
}

// Round 12
// 97.915 us; speedup vs baseline: 1.0120x; 1.0120x over previous
//
#include <hip/hip_runtime.h>

// Sizes (fixed by the problem)
#define NB 16
#define NQ 128
#define NK 512
#define NH 128
#define NDV 128

#define KPAD 132  // 128+4 floats: b128 lane*KPAD reads measured 0 conflicts

typedef __attribute__((ext_vector_type(8))) short short8;
typedef __attribute__((ext_vector_type(4))) unsigned short u16x4;  // NOT ushort4: HIP defines that
typedef __attribute__((ext_vector_type(4))) float f32x4;
typedef __attribute__((ext_vector_type(2))) float f32x2;

#define C2LOG2E 2.8853900817779268f  // 2*log2(e): folded into proj epilogue
#define LOG2E   1.4426950408889634f

__device__ __forceinline__ short f2bf(float x) {   // RNE f32 -> bf16
    unsigned u = __float_as_uint(x);
    unsigned r = (u + 0x7fffu + ((u >> 16) & 1u)) >> 16;
    return (short)r;
}
__device__ __forceinline__ float bf2f(unsigned short s) {
    return __uint_as_float(((unsigned)s) << 16);
}

// ---------------------------------------------------------------------------
// r12 = r10 verbatim (98.3us, session best). r11's 8q-row av (1 block/CU,
// no backfill against nv-imbalance) regressed -0.75us -> reverted; av
// reuse lever closed. All structural levers now measured:
//   confirmed wins: r2 av-restructure +2.7 | r4 scalar-pipe +1.0 |
//                   r10 bf16-P +0.9
//   closed: r3 fusion -9 | r6/r8 occupancy -1.5 | r5 fold 0 | r11 reuse -0.75
//   tanh identity: sum_h wv*tanh(q+k) = Wsum - sum_h 2wv/(Eq*Ek+1),
//   Eq/Ek = exp2(2log2e * proj); masked softmax exploits exact-0 underflow.
// Poison-hardening: Ek rows >= nv zeroed in score; av guarded tail.
// Harness re-poison floor ~65us of dur_us.
// ---------------------------------------------------------------------------

// ---------------------------------------------------------------------------
// Kernel 1: pack W into MFMA B-fragment order, split bf16 hi/lo.
// ---------------------------------------------------------------------------
__global__ __launch_bounds__(256) void wsplit_kernel(
    const float* __restrict__ Wq, const float* __restrict__ Wk,
    const float* __restrict__ wv,
    short* __restrict__ pqh, short* __restrict__ pql,
    short* __restrict__ pkh, short* __restrict__ pkl,
    float* __restrict__ w2)
{
    int blk = blockIdx.x;          // 16 blocks = w(2) x ht(8)
    int t   = threadIdx.x;         // ks(4) x lane(64)
    if (blk == 0 && t < NH) w2[t] = 2.0f * wv[t];
    int w = blk >> 3, ht = blk & 7;
    int ks = t >> 6, lane = t & 63;
    int m = lane & 15, quad = lane >> 4;
    const float* W = w ? Wk : Wq;
    short* ph = w ? pkh : pqh;
    short* pl = w ? pkl : pql;
    short8 hi, lo;
#pragma unroll
    for (int j = 0; j < 8; ++j) {
        float x = W[(size_t)(ks * 32 + quad * 8 + j) * NH + ht * 16 + m];
        short h = f2bf(x);
        hi[j] = h;
        lo[j] = f2bf(x - bf2f((unsigned short)h));
    }
    size_t o = (size_t)((ht * 4 + ks) * 64 + lane) * 8;
    *(short8*)(ph + o) = hi;
    *(short8*)(pl + o) = lo;
}

// ---------------------------------------------------------------------------
// Kernel 2: projection + exp. E = exp2(2log2e * X@W), split-bf16 MFMA
// (Ah*Bh + Al*Bh + Ah*Bh, rel err ~2^-16). X tile staged once in LDS.
// ---------------------------------------------------------------------------
__global__ __launch_bounds__(256) void proj_kernel(
    const float* __restrict__ Xq, const float* __restrict__ Xk,
    const short* __restrict__ pqh, const short* __restrict__ pql,
    const short* __restrict__ pkh, const short* __restrict__ pkl,
    float* __restrict__ Eq, float* __restrict__ Ek)
{
    __shared__ float s_x[16 * KPAD];     // 8448 B

    int blk = blockIdx.x;
    const float* X; const short* ph; const short* pl; float* Y; int row0;
    if (blk < 128) { X = Xq; ph = pqh; pl = pql; Y = Eq; row0 = blk * 16; }
    else           { X = Xk; ph = pkh; pl = pkl; Y = Ek; row0 = (blk - 128) * 16; }
    int t = threadIdx.x;
    int wave = t >> 6, lane = t & 63;
    int m = lane & 15, quad = lane >> 4;

#pragma unroll
    for (int r = 0; r < 2; ++r) {
        int i = (t + r * 256) * 4;
        int row = i >> 7, col = i & 127;
        *(f32x4*)&s_x[row * KPAD + col] =
            *(const f32x4*)&X[(size_t)(row0 + row) * NH + col];
    }
    __syncthreads();

    short8 AH[4], AL[4];
#pragma unroll
    for (int ks = 0; ks < 4; ++ks) {
        int base = m * KPAD + ks * 32 + quad * 8;
        f32x4 x0 = *(const f32x4*)&s_x[base];
        f32x4 x1 = *(const f32x4*)&s_x[base + 4];
#pragma unroll
        for (int j = 0; j < 4; ++j) {
            short h0 = f2bf(x0[j]);
            AH[ks][j] = h0; AL[ks][j] = f2bf(x0[j] - bf2f((unsigned short)h0));
            short h1 = f2bf(x1[j]);
            AH[ks][j + 4] = h1; AL[ks][j + 4] = f2bf(x1[j] - bf2f((unsigned short)h1));
        }
    }
#pragma unroll
    for (int hi = 0; hi < 2; ++hi) {
        int ht = wave * 2 + hi;
        f32x4 acc = {0.f, 0.f, 0.f, 0.f};
#pragma unroll
        for (int ks = 0; ks < 4; ++ks) {
            size_t o = (size_t)((ht * 4 + ks) * 64 + lane) * 8;
            short8 bh = *(const short8*)(ph + o);
            short8 bl = *(const short8*)(pl + o);
            acc = __builtin_amdgcn_mfma_f32_16x16x32_bf16(AH[ks], bl, acc, 0, 0, 0);
            acc = __builtin_amdgcn_mfma_f32_16x16x32_bf16(AL[ks], bh, acc, 0, 0, 0);
            acc = __builtin_amdgcn_mfma_f32_16x16x32_bf16(AH[ks], bh, acc, 0, 0, 0);
        }
        // D: col = lane&15, row = quad*4 + r  [verified layout]
#pragma unroll
        for (int r = 0; r < 4; ++r)
            Y[(size_t)(row0 + quad * 4 + r) * NH + ht * 16 + m] =
                __builtin_amdgcn_exp2f(acc[r] * C2LOG2E);
    }
}

// ---------------------------------------------------------------------------
// Kernel 3 (r4 config): scores. Packed-f32 inner loop + pair-reciprocal,
// wave-uniform operands (q rows, w2) via the scalar pipe. Grid 512 =
// b(16) x qt(8) x kc(4); 512 thr; s_ek 67.5 KB. P stored as bf16 (r10).
// s_ek rows >= nv zeroed at staging (poison-hard).
// ---------------------------------------------------------------------------
__global__ __launch_bounds__(512) void score_kernel(
    const float* __restrict__ Eqp, const float* __restrict__ Ekp,
    const int* __restrict__ vlen, const float* __restrict__ w2,
    short* __restrict__ Pbf)
{
    __shared__ float s_ek[128 * KPAD];   // 67584 B (only LDS in this kernel)

    int blk = blockIdx.x;
    int b    = blk & 15;                 // batch-interleaved
    int rest = blk >> 4;
    int qt = rest & 7, kc = rest >> 3;   // qt 0..7 (16q each), kc 0..3 (128k)
    int q0 = qt * 16, k0 = kc * 128;
    int t  = threadIdx.x;

    int nv = vlen[b];
    nv = max(1, min(NK, nv));
    short* Pb = Pbf + ((size_t)b * NQ + q0) * NK;

    if (k0 >= nv) {
        // fully masked chunk: 16q x 128k = 2048 bf16 = one u16x4/thread
        int q = t >> 5, kk = (t & 31) * 4;
        u16x4 z = {0, 0, 0, 0};
        *(u16x4*)&Pb[(size_t)q * NK + k0 + kk] = z;
        return;
    }

    for (int i = t; i < 128 * 32; i += 512) {
        int row = i >> 5, c4 = i & 31;
        f32x4 v = *(const f32x4*)&Ekp[((size_t)b * NK + k0 + row) * NH + c4 * 4];
        if (k0 + row >= nv) {            // sanitize don't-care keys rows
            f32x4 z = {0.f, 0.f, 0.f, 0.f};
            v = z;
        }
        *(f32x4*)&s_ek[row * KPAD + c4 * 4] = v;
    }
    __syncthreads();

    int lane = t & 63, w = t >> 6;
    int wu = __builtin_amdgcn_readfirstlane(w);  // provably uniform
    int g = wu & 3, hf = wu >> 2;

    // Wsum = sum_h wv = 0.5 * sum_h w2 (one-time per-lane global read)
    float s2 = w2[lane] + w2[lane + 64];
#pragma unroll
    for (int off = 32; off; off >>= 1) s2 += __shfl_xor(s2, off);
    float wsum = 0.5f * s2;

    const float* ek = &s_ek[(hf * 64 + lane) * KPAD];
    // uniform scalar bases for the 4 q-rows of this wave
    const float* e0 = Eqp + ((size_t)b * NQ + q0 + g * 4 + 0) * NH;
    const float* e1 = Eqp + ((size_t)b * NQ + q0 + g * 4 + 1) * NH;
    const float* e2 = Eqp + ((size_t)b * NQ + q0 + g * 4 + 2) * NH;
    const float* e3 = Eqp + ((size_t)b * NQ + q0 + g * 4 + 3) * NH;

    const f32x2 one2 = {1.0f, 1.0f};
    f32x2 v00 = {0.f, 0.f}, v01 = {0.f, 0.f};
    f32x2 v10 = {0.f, 0.f}, v11 = {0.f, 0.f};
    f32x2 v20 = {0.f, 0.f}, v21 = {0.f, 0.f};
    f32x2 v30 = {0.f, 0.f}, v31 = {0.f, 0.f};

#define PKSTEP(accv, qv, kv, wv)                                        \
    {                                                                   \
        f32x2 x = qv * kv + one2;                                       \
        float R = __builtin_amdgcn_rcpf(x[0] * x[1]);                   \
        f32x2 xs = {x[1], x[0]};                                        \
        accv += wv * (R * xs);                                          \
    }

#pragma unroll
    for (int hh = 0; hh < NH; hh += 8) {
        f32x4 kAv = *(const f32x4*)(ek + hh);          // per-lane LDS
        f32x4 kBv = *(const f32x4*)(ek + hh + 4);
        f32x4 wAv = *(const f32x4*)(w2 + hh);          // uniform -> s_load
        f32x4 wBv = *(const f32x4*)(w2 + hh + 4);
        f32x2 kA0 = {kAv[0], kAv[1]}, kA1 = {kAv[2], kAv[3]};
        f32x2 kB0 = {kBv[0], kBv[1]}, kB1 = {kBv[2], kBv[3]};
        f32x2 wA0 = {wAv[0], wAv[1]}, wA1 = {wAv[2], wAv[3]};
        f32x2 wB0 = {wBv[0], wBv[1]}, wB1 = {wBv[2], wBv[3]};
        {
            f32x4 qa = *(const f32x4*)(e0 + hh), qb = *(const f32x4*)(e0 + hh + 4);
            f32x2 qa0 = {qa[0], qa[1]}, qa1 = {qa[2], qa[3]};
            f32x2 qb0 = {qb[0], qb[1]}, qb1 = {qb[2], qb[3]};
            PKSTEP(v00, qa0, kA0, wA0); PKSTEP(v01, qa1, kA1, wA1);
            PKSTEP(v00, qb0, kB0, wB0); PKSTEP(v01, qb1, kB1, wB1);
        }
        {
            f32x4 qa = *(const f32x4*)(e1 + hh), qb = *(const f32x4*)(e1 + hh + 4);
            f32x2 qa0 = {qa[0], qa[1]}, qa1 = {qa[2], qa[3]};
            f32x2 qb0 = {qb[0], qb[1]}, qb1 = {qb[2], qb[3]};
            PKSTEP(v10, qa0, kA0, wA0); PKSTEP(v11, qa1, kA1, wA1);
            PKSTEP(v10, qb0, kB0, wB0); PKSTEP(v11, qb1, kB1, wB1);
        }
        {
            f32x4 qa = *(const f32x4*)(e2 + hh), qb = *(const f32x4*)(e2 + hh + 4);
            f32x2 qa0 = {qa[0], qa[1]}, qa1 = {qa[2], qa[3]};
            f32x2 qb0 = {qb[0], qb[1]}, qb1 = {qb[2], qb[3]};
            PKSTEP(v20, qa0, kA0, wA0); PKSTEP(v21, qa1, kA1, wA1);
            PKSTEP(v20, qb0, kB0, wB0); PKSTEP(v21, qb1, kB1, wB1);
        }
        {
            f32x4 qa = *(const f32x4*)(e3 + hh), qb = *(const f32x4*)(e3 + hh + 4);
            f32x2 qa0 = {qa[0], qa[1]}, qa1 = {qa[2], qa[3]};
            f32x2 qb0 = {qb[0], qb[1]}, qb1 = {qb[2], qb[3]};
            PKSTEP(v30, qa0, kA0, wA0); PKSTEP(v31, qa1, kA1, wA1);
            PKSTEP(v30, qb0, kB0, wB0); PKSTEP(v31, qb1, kB1, wB1);
        }
    }
#undef PKSTEP
    float c0 = (v00[0] + v00[1]) + (v01[0] + v01[1]);
    float c1 = (v10[0] + v10[1]) + (v11[0] + v11[1]);
    float c2 = (v20[0] + v20[1]) + (v21[0] + v21[1]);
    float c3 = (v30[0] + v30[1]) + (v31[0] + v31[1]);
    int kg = k0 + hf * 64 + lane;
    bool valid = kg < nv;
    float p0 = valid ? __builtin_amdgcn_exp2f((wsum - c0) * LOG2E) : 0.f;
    float p1 = valid ? __builtin_amdgcn_exp2f((wsum - c1) * LOG2E) : 0.f;
    float p2 = valid ? __builtin_amdgcn_exp2f((wsum - c2) * LOG2E) : 0.f;
    float p3 = valid ? __builtin_amdgcn_exp2f((wsum - c3) * LOG2E) : 0.f;
    short* Pr = Pb + (size_t)(g * 4) * NK + kg;
    Pr[0 * NK] = f2bf(p0);               // coalesced 2B stores per q-row
    Pr[1 * NK] = f2bf(p1);
    Pr[2 * NK] = f2bf(p2);
    Pr[3 * NK] = f2bf(p3);
}

// ---------------------------------------------------------------------------
// Kernel 4 (r2 form): normalize + AV. P read as bf16, converted to f32 at
// LDS staging; row sums + inner loop in f32.
// 512 blocks x 512 threads: block = (b, 4 q-rows); k split across 8 waves in
// interleaved 8-row strips so all waves stay busy for any nv. 4 q-rows
// share each V load. Cross-wave LDS reduce. Poison-proof: full strips touch
// only rows < nv; partial strip selects V rows >= nv to 0.
// ---------------------------------------------------------------------------
__global__ __launch_bounds__(512, 4) void av_kernel(
    const short* __restrict__ Pbf, const float* __restrict__ V,
    const int* __restrict__ vlen, float* __restrict__ out)
{
    __shared__ float s_p[4 * NK];          //  8 KB: 4 q-rows of P (f32)
    __shared__ float s_red[8 * 4 * 128];   // 16 KB: per-wave partial O
    __shared__ float s_rsum[4];

    int blk = blockIdx.x;
    int b = blk & 15, qq = blk >> 4;       // qq 0..31 (4 q each)
    int q0 = qq * 4;
    int t = threadIdx.x;

    int nv = vlen[b];
    nv = max(1, min(NK, nv));

    // stage 4 P rows: 2048 bf16 = 512 u16x4, one per thread; cvt to f32
    const u16x4* Pv = (const u16x4*)(Pbf + ((size_t)b * NQ + q0) * NK);
    {
        u16x4 pv = Pv[t];
        f32x4 pf = {bf2f(pv[0]), bf2f(pv[1]), bf2f(pv[2]), bf2f(pv[3])};
        *(f32x4*)&s_p[t * 4] = pf;
    }
    __syncthreads();

    int lane = t & 63, w = t >> 6;

    if (w < 4) {                           // row sum for row w (zeros beyond
        const float* pr = &s_p[w * NK];    //  nv are exact -> sum exact)
        f32x4 s0 = *(const f32x4*)(pr + lane * 8);
        f32x4 s1 = *(const f32x4*)(pr + lane * 8 + 4);
        float s = ((s0[0] + s0[1]) + (s0[2] + s0[3])) +
                  ((s1[0] + s1[1]) + (s1[2] + s1[3]));
#pragma unroll
        for (int off = 32; off; off >>= 1) s += __shfl_xor(s, off);
        if (lane == 0) s_rsum[w] = s;      // read after final barrier
    }

    int par = lane >> 5;                   // k parity for this half-wave
    int dl  = lane & 31;
    int dv0 = dl * 4;                      // 4 dv per lane (f32x4)
    const float* Vb = V + (size_t)b * NK * NDV + dv0;
    const float* pa = &s_p[0 * NK];
    const float* pb = &s_p[1 * NK];
    const float* pc = &s_p[2 * NK];
    const float* pd = &s_p[3 * NK];
    f32x4 Oa = {0.f, 0.f, 0.f, 0.f};
    f32x4 Ob = {0.f, 0.f, 0.f, 0.f};
    f32x4 Oc = {0.f, 0.f, 0.f, 0.f};
    f32x4 Od = {0.f, 0.f, 0.f, 0.f};

    int k = w * 8;                         // interleaved strips, stride 64
    for (; k + 8 <= nv; k += 64) {
        f32x4 pA0 = *(const f32x4*)(pa + k);         // LDS broadcasts
        f32x4 pA1 = *(const f32x4*)(pa + k + 4);
        f32x4 pB0 = *(const f32x4*)(pb + k);
        f32x4 pB1 = *(const f32x4*)(pb + k + 4);
        f32x4 pC0 = *(const f32x4*)(pc + k);
        f32x4 pC1 = *(const f32x4*)(pc + k + 4);
        f32x4 pD0 = *(const f32x4*)(pd + k);
        f32x4 pD1 = *(const f32x4*)(pd + k + 4);
        f32x4 v0 = *(const f32x4*)(Vb + (size_t)(k + 0 + par) * NDV);
        f32x4 v1 = *(const f32x4*)(Vb + (size_t)(k + 2 + par) * NDV);
        f32x4 v2 = *(const f32x4*)(Vb + (size_t)(k + 4 + par) * NDV);
        f32x4 v3 = *(const f32x4*)(Vb + (size_t)(k + 6 + par) * NDV);
        float a0 = pA0[par], a1 = pA0[2 + par], a2 = pA1[par], a3 = pA1[2 + par];
        float b0 = pB0[par], b1 = pB0[2 + par], b2 = pB1[par], b3 = pB1[2 + par];
        float c0 = pC0[par], c1 = pC0[2 + par], c2 = pC1[par], c3 = pC1[2 + par];
        float d0 = pD0[par], d1 = pD0[2 + par], d2 = pD1[par], d3 = pD1[2 + par];
#pragma unroll
        for (int j = 0; j < 4; ++j) {
            Oa[j] = fmaf(a0, v0[j], Oa[j]); Ob[j] = fmaf(b0, v0[j], Ob[j]);
            Oc[j] = fmaf(c0, v0[j], Oc[j]); Od[j] = fmaf(d0, v0[j], Od[j]);
            Oa[j] = fmaf(a1, v1[j], Oa[j]); Ob[j] = fmaf(b1, v1[j], Ob[j]);
            Oc[j] = fmaf(c1, v1[j], Oc[j]); Od[j] = fmaf(d1, v1[j], Od[j]);
            Oa[j] = fmaf(a2, v2[j], Oa[j]); Ob[j] = fmaf(b2, v2[j], Ob[j]);
            Oc[j] = fmaf(c2, v2[j], Oc[j]); Od[j] = fmaf(d2, v2[j], Od[j]);
            Oa[j] = fmaf(a3, v3[j], Oa[j]); Ob[j] = fmaf(b3, v3[j], Ob[j]);
            Oc[j] = fmaf(c3, v3[j], Oc[j]); Od[j] = fmaf(d3, v3[j], Od[j]);
        }
    }
    if (k < nv) {                          // partial strip: guarded tail
        f32x4 z4 = {0.f, 0.f, 0.f, 0.f};
        f32x4 pA0 = *(const f32x4*)(pa + k);
        f32x4 pA1 = *(const f32x4*)(pa + k + 4);
        f32x4 pB0 = *(const f32x4*)(pb + k);
        f32x4 pB1 = *(const f32x4*)(pb + k + 4);
        f32x4 pC0 = *(const f32x4*)(pc + k);
        f32x4 pC1 = *(const f32x4*)(pc + k + 4);
        f32x4 pD0 = *(const f32x4*)(pd + k);
        f32x4 pD1 = *(const f32x4*)(pd + k + 4);
        f32x4 v0 = *(const f32x4*)(Vb + (size_t)(k + 0 + par) * NDV);
        f32x4 v1 = *(const f32x4*)(Vb + (size_t)(k + 2 + par) * NDV);
        f32x4 v2 = *(const f32x4*)(Vb + (size_t)(k + 4 + par) * NDV);
        f32x4 v3 = *(const f32x4*)(Vb + (size_t)(k + 6 + par) * NDV);
        if (k + 0 + par >= nv) v0 = z4;    // poison-proof: p==0 rows get v==0
        if (k + 2 + par >= nv) v1 = z4;
        if (k + 4 + par >= nv) v2 = z4;
        if (k + 6 + par >= nv) v3 = z4;
        float a0 = pA0[par], a1 = pA0[2 + par], a2 = pA1[par], a3 = pA1[2 + par];
        float b0 = pB0[par], b1 = pB0[2 + par], b2 = pB1[par], b3 = pB1[2 + par];
        float c0 = pC0[par], c1 = pC0[2 + par], c2 = pC1[par], c3 = pC1[2 + par];
        float d0 = pD0[par], d1 = pD0[2 + par], d2 = pD1[par], d3 = pD1[2 + par];
#pragma unroll
        for (int j = 0; j < 4; ++j) {
            Oa[j] = fmaf(a0, v0[j], Oa[j]); Ob[j] = fmaf(b0, v0[j], Ob[j]);
            Oc[j] = fmaf(c0, v0[j], Oc[j]); Od[j] = fmaf(d0, v0[j], Od[j]);
            Oa[j] = fmaf(a1, v1[j], Oa[j]); Ob[j] = fmaf(b1, v1[j], Ob[j]);
            Oc[j] = fmaf(c1, v1[j], Oc[j]); Od[j] = fmaf(d1, v1[j], Od[j]);
            Oa[j] = fmaf(a2, v2[j], Oa[j]); Ob[j] = fmaf(b2, v2[j], Ob[j]);
            Oc[j] = fmaf(c2, v2[j], Oc[j]); Od[j] = fmaf(d2, v2[j], Od[j]);
            Oa[j] = fmaf(a3, v3[j], Oa[j]); Ob[j] = fmaf(b3, v3[j], Ob[j]);
            Oc[j] = fmaf(c3, v3[j], Oc[j]); Od[j] = fmaf(d3, v3[j], Od[j]);
        }
    }
    // combine even/odd k-parity partial sums across the half-waves
#pragma unroll
    for (int j = 0; j < 4; ++j) {
        Oa[j] += __shfl_xor(Oa[j], 32);
        Ob[j] += __shfl_xor(Ob[j], 32);
        Oc[j] += __shfl_xor(Oc[j], 32);
        Od[j] += __shfl_xor(Od[j], 32);
    }
    // per-wave partials to LDS: par0 lanes carry rows 0,1; par1 rows 2,3
    float* rb = &s_red[w * 512];
    if (par == 0) {
        *(f32x4*)&rb[0 * 128 + dv0] = Oa;
        *(f32x4*)&rb[1 * 128 + dv0] = Ob;
    } else {
        *(f32x4*)&rb[2 * 128 + dv0] = Oc;
        *(f32x4*)&rb[3 * 128 + dv0] = Od;
    }
    __syncthreads();

    // final reduce + normalize: one output scalar per thread (4 rows x 128 dv)
    int row = t >> 7, dv = t & 127;
    float s = 0.f;
#pragma unroll
    for (int ww = 0; ww < 8; ++ww) s += s_red[ww * 512 + row * 128 + dv];
    out[((size_t)b * NQ + q0 + row) * NDV + dv] = s * (1.0f / s_rsum[row]);
}

extern "C" void kernel_launch(void* const* d_in, const int* in_sizes, int n_in,
                              void* d_out, int out_size, void* d_ws, size_t ws_size,
                              hipStream_t stream) {
    const float* q  = (const float*)d_in[0];  // (16,128,128) f32
    const float* ks = (const float*)d_in[1];  // (16,512,128) f32
    const float* vs = (const float*)d_in[2];  // (16,512,128) f32
    const int*   vl = (const int*)d_in[3];    // (16,) i32
    const float* wq = (const float*)d_in[4];  // (128,128) f32
    const float* wk = (const float*)d_in[5];  // (128,128) f32
    const float* wv = (const float*)d_in[6];  // (128,) f32

    // ws layout (~7.3 MiB; P is bf16)
    float* Eq  = (float*)d_ws;                    // 2048*128 f32
    float* Ek  = Eq + 2048 * 128;                 // 8192*128 f32
    short* Pbf = (short*)(Ek + (size_t)8192 * 128);  // 16*128*512 bf16 (2 MB)
    float* w2  = (float*)(Pbf + (size_t)NB * NQ * NK);  // 128 f32
    short* pqh = (short*)(w2 + 128);              // 4 x 16384 bf16 frags
    short* pql = pqh + 16384;
    short* pkh = pql + 16384;
    short* pkl = pkh + 16384;

    wsplit_kernel<<<16, 256, 0, stream>>>(wq, wk, wv, pqh, pql, pkh, pkl, w2);
    proj_kernel<<<640, 256, 0, stream>>>(q, ks, pqh, pql, pkh, pkl, Eq, Ek);
    score_kernel<<<512, 512, 0, stream>>>(Eq, Ek, vl, w2, Pbf);
    av_kernel<<<512, 512, 0, stream>>>(Pbf, vs, vl, (float*)d_out);
}